// Round 2
// baseline (4429.418 us; speedup 1.0000x reference)
//
#include <hip/hip_runtime.h>
#include <stdint.h>

#define EPSF 1e-5f

__device__ __forceinline__ float softplus_f(float x) {
    return x > 20.f ? x : log1pf(expf(x));
}

// ---------------- fp32 SIMT GEMM: C[M][N] = A[M][K] * B[N][K]^T ----------------
// 64x64 tile per block, 256 threads, 4x4 per thread, K-step 16. Diagnostic: no
// bf16, no MFMA, no inline asm — removes the entire matrix-core risk surface.
__global__ __launch_bounds__(256) void k_gemm_nt_f32(const float* __restrict__ A,
                                                     const float* __restrict__ B,
                                                     float* __restrict__ C,
                                                     int M, int N, int K) {
    __shared__ float As[16][68];   // [k][m], pad 68 -> 16B-aligned rows, 2-way banks
    __shared__ float Bs[16][68];   // [k][n]
    const int tid = threadIdx.x;
    const int tx = tid & 15, ty = tid >> 4;
    const int nbx = N >> 6;
    const int bx = blockIdx.x % nbx;
    const int by = blockIdx.x / nbx;
    const int row0 = by * 64, col0 = bx * 64;

    float acc[4][4] = {};

    for (int kk = 0; kk < K; kk += 16) {
#pragma unroll
        for (int l = 0; l < 4; l++) {
            int idx = tid + l * 256;          // 0..1023
            int r = idx >> 4, c = idx & 15;
            As[c][r] = A[(size_t)(row0 + r) * K + kk + c];
            Bs[c][r] = B[(size_t)(col0 + r) * K + kk + c];
        }
        __syncthreads();
#pragma unroll
        for (int k = 0; k < 16; k++) {
            float a0 = As[k][ty * 4 + 0], a1 = As[k][ty * 4 + 1];
            float a2 = As[k][ty * 4 + 2], a3 = As[k][ty * 4 + 3];
            float b0 = Bs[k][tx * 4 + 0], b1 = Bs[k][tx * 4 + 1];
            float b2 = Bs[k][tx * 4 + 2], b3 = Bs[k][tx * 4 + 3];
            acc[0][0] += a0 * b0; acc[0][1] += a0 * b1; acc[0][2] += a0 * b2; acc[0][3] += a0 * b3;
            acc[1][0] += a1 * b0; acc[1][1] += a1 * b1; acc[1][2] += a1 * b2; acc[1][3] += a1 * b3;
            acc[2][0] += a2 * b0; acc[2][1] += a2 * b1; acc[2][2] += a2 * b2; acc[2][3] += a2 * b3;
            acc[3][0] += a3 * b0; acc[3][1] += a3 * b1; acc[3][2] += a3 * b2; acc[3][3] += a3 * b3;
        }
        __syncthreads();
    }
#pragma unroll
    for (int mm = 0; mm < 4; mm++)
#pragma unroll
        for (int nn = 0; nn < 4; nn++)
            C[(size_t)(row0 + ty * 4 + mm) * N + col0 + tx * 4 + nn] = acc[mm][nn];
}

// ---------------- exp_map on Q or K (in place) + ||y||^2 per (h,n) ----------------
// QK layout [n][h*64+d] fp32; ns layout [h*2048+n]
__global__ __launch_bounds__(256) void k_expmap(float* __restrict__ QK,
                                                float* __restrict__ ns,
                                                const float* __restrict__ pLogC) {
    float c  = softplus_f(pLogC[0]);
    float sc = sqrtf(c);
    int gid  = (blockIdx.x * 256 + threadIdx.x) >> 6;   // 0..32767
    int lane = threadIdx.x & 63;
    int n = gid >> 4, h = gid & 15;
    size_t idx = (size_t)n * 1024 + h * 64 + lane;
    float v  = QK[idx];
    float n2 = v * v;
#pragma unroll
    for (int o = 1; o < 64; o <<= 1) n2 += __shfl_xor(n2, o);
    float nn = fmaxf(sqrtf(n2), EPSF);
    float f  = tanhf(sc * nn) / (sc * nn);
    QK[idx]  = f * v;
    if (lane == 0) ns[h * 2048 + n] = f * f * n2;
}

// ---------------- fused attention (fp32 SIMT, 1 wave per (h,i)) ----------------
__global__ __launch_bounds__(256) void k_attn(const float* __restrict__ Qe,
                                              const float* __restrict__ Ke,
                                              const float* __restrict__ Vf,
                                              const float* __restrict__ xns,
                                              const float* __restrict__ yns,
                                              const float* __restrict__ pLogC,
                                              const float* __restrict__ pBeta,
                                              const float* __restrict__ pBias,
                                              float* __restrict__ conc) {
    const float c      = softplus_f(pLogC[0]);
    const float sc     = sqrtf(c);
    const float inv_sc = 1.f / sc;
    const float bpos   = softplus_f(pBeta[0]);
    const float bias   = pBias[0];
    const int gid  = (blockIdx.x * 256 + threadIdx.x) >> 6;  // 0..32767
    const int lane = threadIdx.x & 63;
    const int h = gid >> 11, i = gid & 2047;

    const float* Kh = Ke + h * 64 + lane;
    const float* Vh = Vf + h * 64 + lane;
    const float* yn = yns + h * 2048;
    const float q   = Qe[(size_t)i * 1024 + h * 64 + lane];
    const float xi  = xns[h * 2048 + i];
    const float dx  = 1.f - c * xi;

    float m = -3.0e38f, l = 0.f, acc = 0.f;
    for (int j = 0; j <= i; ++j) {
        float kv = Kh[(size_t)j * 1024];
        float p  = q * kv;
#pragma unroll
        for (int o = 1; o < 64; o <<= 1) p += __shfl_xor(p, o);
        float yj   = yn[j];
        float diff = xi - 2.f * p + yj;
        float den  = fmaxf(dx * (1.f - c * yj), EPSF);
        float arg  = 1.f + (2.f * c) * diff / den;
        float z    = fmaxf(arg, 1.f + EPSF);
        float dist = __logf(z + sqrtf(z * z - 1.f)) * inv_sc;
        float s    = -bpos * dist - bias;
        float mn   = fmaxf(m, s);
        float esc  = __expf(m - mn);
        float pw   = __expf(s - mn);
        l = l * esc + pw;
        float vv = Vh[(size_t)j * 1024];
        acc = acc * esc + pw * vv;
        m = mn;
    }
    float t  = acc / l;                    // out_tangent (this lane's dim)
    float n2 = t * t;
#pragma unroll
    for (int o = 1; o < 64; o <<= 1) n2 += __shfl_xor(n2, o);
    // exp_map
    float nt = fmaxf(sqrtf(n2), EPSF);
    float f1 = tanhf(sc * nt) / (sc * nt);
    float y  = f1 * t;
    // log_map
    float ny   = fmaxf(f1 * sqrtf(n2), EPSF);
    float ncl  = fminf(ny, inv_sc - EPSF);
    float coef = atanhf(sc * ncl) / (sc * ny);
    conc[(size_t)i * 1024 + h * 64 + lane] = coef * y;
}

// ---------------- launch ----------------
extern "C" void kernel_launch(void* const* d_in, const int* in_sizes, int n_in,
                              void* d_out, int out_size, void* d_ws, size_t ws_size,
                              hipStream_t stream) {
    const float* x     = (const float*)d_in[0];
    const float* Wq    = (const float*)d_in[1];
    const float* Wk    = (const float*)d_in[2];
    const float* Wv    = (const float*)d_in[3];
    const float* Wo    = (const float*)d_in[4];
    const float* pLogC = (const float*)d_in[5];
    const float* pBeta = (const float*)d_in[6];
    const float* pBias = (const float*)d_in[7];
    // d_in[8] = mask: deterministically causal tril, handled implicitly
    float* out = (float*)d_out;

    char* w = (char*)d_ws;
    float* Q    = (float*)(w);                               // 8 MB
    float* Kf   = (float*)(w + (8u  << 20));                 // 8 MB
    float* Vf   = (float*)(w + (16u << 20));                 // 8 MB
    float* conc = (float*)(w + (24u << 20));                 // 8 MB
    float* xns  = (float*)(w + (32u << 20));                 // 128 KB
    float* yns  = (float*)(w + (32u << 20) + (1u << 17));    // 128 KB

    k_gemm_nt_f32<<<512, 256, 0, stream>>>(x, Wq, Q,  2048, 1024, 1024);
    k_gemm_nt_f32<<<512, 256, 0, stream>>>(x, Wk, Kf, 2048, 1024, 1024);
    k_gemm_nt_f32<<<512, 256, 0, stream>>>(x, Wv, Vf, 2048, 1024, 1024);

    k_expmap<<<8192, 256, 0, stream>>>(Q,  xns, pLogC);
    k_expmap<<<8192, 256, 0, stream>>>(Kf, yns, pLogC);

    k_attn<<<8192, 256, 0, stream>>>(Q, Kf, Vf, xns, yns, pLogC, pBeta, pBias, conc);

    k_gemm_nt_f32<<<512, 256, 0, stream>>>(conc, Wo, out, 2048, 1024, 1024);
}

// Round 4
// 627.306 us; speedup vs baseline: 7.0610x; 7.0610x over previous
//
#include <hip/hip_runtime.h>
#include <stdint.h>

#define EPSF 1e-5f

__device__ __forceinline__ float softplus_f(float x) {
    return x > 20.f ? x : log1pf(expf(x));
}

// ---------------- fp32 SIMT GEMM: C[M][N] = A[M][K] * B[N][K]^T ----------------
// (verified in round 2 — unchanged)
__global__ __launch_bounds__(256) void k_gemm_nt_f32(const float* __restrict__ A,
                                                     const float* __restrict__ B,
                                                     float* __restrict__ C,
                                                     int M, int N, int K) {
    __shared__ float As[16][68];
    __shared__ float Bs[16][68];
    const int tid = threadIdx.x;
    const int tx = tid & 15, ty = tid >> 4;
    const int nbx = N >> 6;
    const int bx = blockIdx.x % nbx;
    const int by = blockIdx.x / nbx;
    const int row0 = by * 64, col0 = bx * 64;

    float acc[4][4] = {};

    for (int kk = 0; kk < K; kk += 16) {
#pragma unroll
        for (int l = 0; l < 4; l++) {
            int idx = tid + l * 256;
            int r = idx >> 4, c = idx & 15;
            As[c][r] = A[(size_t)(row0 + r) * K + kk + c];
            Bs[c][r] = B[(size_t)(col0 + r) * K + kk + c];
        }
        __syncthreads();
#pragma unroll
        for (int k = 0; k < 16; k++) {
            float a0 = As[k][ty * 4 + 0], a1 = As[k][ty * 4 + 1];
            float a2 = As[k][ty * 4 + 2], a3 = As[k][ty * 4 + 3];
            float b0 = Bs[k][tx * 4 + 0], b1 = Bs[k][tx * 4 + 1];
            float b2 = Bs[k][tx * 4 + 2], b3 = Bs[k][tx * 4 + 3];
            acc[0][0] += a0 * b0; acc[0][1] += a0 * b1; acc[0][2] += a0 * b2; acc[0][3] += a0 * b3;
            acc[1][0] += a1 * b0; acc[1][1] += a1 * b1; acc[1][2] += a1 * b2; acc[1][3] += a1 * b3;
            acc[2][0] += a2 * b0; acc[2][1] += a2 * b1; acc[2][2] += a2 * b2; acc[2][3] += a2 * b3;
            acc[3][0] += a3 * b0; acc[3][1] += a3 * b1; acc[3][2] += a3 * b2; acc[3][3] += a3 * b3;
        }
        __syncthreads();
    }
#pragma unroll
    for (int mm = 0; mm < 4; mm++)
#pragma unroll
        for (int nn = 0; nn < 4; nn++)
            C[(size_t)(row0 + ty * 4 + mm) * N + col0 + tx * 4 + nn] = acc[mm][nn];
}

// ---------------- exp_map (in place) + ||y||^2 + STABLE (1 - c||y||^2) ----------------
// QK layout [n][h*64+d] fp32; ns/ds layout [h*2048+n].
// ds = 1 - c*xn = sech^2(sqrt(c)*||v||) computed via exp(-2u): NO cancellation
// (the subtractive form 1 - c*xn loses ~0.45% rel. accuracy at dx ~ 2e-4 and was
// the dominant absmax contributor through the per-key -ln(dy) score term).
__global__ __launch_bounds__(256) void k_expmap(float* __restrict__ QK,
                                                float* __restrict__ ns,
                                                float* __restrict__ ds,
                                                const float* __restrict__ pLogC) {
    float c  = softplus_f(pLogC[0]);
    float sc = sqrtf(c);
    int gid  = (blockIdx.x * 256 + threadIdx.x) >> 6;
    int lane = threadIdx.x & 63;
    int n = gid >> 4, h = gid & 15;
    size_t idx = (size_t)n * 1024 + h * 64 + lane;
    float v  = QK[idx];
    float n2 = v * v;
#pragma unroll
    for (int o = 1; o < 64; o <<= 1) n2 += __shfl_xor(n2, o);
    float nn = fmaxf(sqrtf(n2), EPSF);
    float u  = sc * nn;
    float e  = __expf(-2.f * u);               // u > 0 here
    float th = (1.f - e) / (1.f + e);          // tanh(u), stable
    float f  = th / (sc * nn);
    QK[idx]  = f * v;
    if (lane == 0) {
        float xn = f * f * n2;
        ns[h * 2048 + n] = xn;
        float op = 1.f + e;
        float sech2 = 4.f * e / (op * op);     // 1 - tanh^2(u), no cancellation
        // tiny-norm fallback (never hit at this data scale, kept for exactness):
        ds[h * 2048 + n] = (n2 < 1e-6f) ? (1.f - c * xn) : sech2;
    }
}

// ---------------- tiled flash-style attention (fp32 SIMT) ----------------
// Block = (head h, 64 q-rows). 256 threads = 16x16, each owns a 4x4 micro-tile.
// LDS: Qt[d][m], KPt (K^T during S / P^T during PV — union), Vs[j][d]. ~53 KB -> 3 blocks/CU.
__global__ __launch_bounds__(256) void k_attn_tiled(const float* __restrict__ Qe,
                                                    const float* __restrict__ Ke,
                                                    const float* __restrict__ Vf,
                                                    const float* __restrict__ xns,
                                                    const float* __restrict__ xds,
                                                    const float* __restrict__ yns,
                                                    const float* __restrict__ yds,
                                                    const float* __restrict__ pLogC,
                                                    const float* __restrict__ pBeta,
                                                    const float* __restrict__ pBias,
                                                    float* __restrict__ conc) {
    __shared__ float Qt[64][68];    // Q^T tile: [d][m]
    __shared__ float KPt[64][68];   // K^T tile [d][n] during S; P^T [j][m] during PV
    __shared__ float Vs[64][68];    // V tile: [j][d]
    __shared__ float yl[64];        // yns for this kv tile
    __shared__ float ydl[64];       // yds (stable 1-c*yn) for this kv tile

    const float c      = softplus_f(pLogC[0]);
    const float sc     = sqrtf(c);
    const float inv_sc = 1.f / sc;
    const float bpos   = softplus_f(pBeta[0]);
    const float bias   = pBias[0];

    const int bid = blockIdx.x;
    const int qt  = bid >> 4;        // q-tile 0..31
    const int h   = bid & 15;
    const int q0  = qt << 6;
    const int tid = threadIdx.x;
    const int tx  = tid & 15, ty = tid >> 4;
    const int m0  = ty * 4;          // q-row block
    const int d0  = tx * 4;          // kv-col block (S phase) / dim block (PV phase)

    // stage Q^T (once per block)
#pragma unroll
    for (int p = 0; p < 4; p++) {
        int m = p * 16 + ty;
        float4 g = *(const float4*)&Qe[(size_t)(q0 + m) * 1024 + h * 64 + d0];
        Qt[d0 + 0][m] = g.x; Qt[d0 + 1][m] = g.y; Qt[d0 + 2][m] = g.z; Qt[d0 + 3][m] = g.w;
    }

    float xi[4], dxr[4], mrow[4], lrow[4];
#pragma unroll
    for (int r = 0; r < 4; r++) {
        xi[r]   = xns[h * 2048 + q0 + m0 + r];
        dxr[r]  = xds[h * 2048 + q0 + m0 + r];   // stable 1 - c*xn
        mrow[r] = -3.0e38f;
        lrow[r] = 0.f;
    }
    float acc[4][4] = {};

    for (int jt = 0; jt <= qt; ++jt) {
        const int k0 = jt << 6;
        __syncthreads();   // Qt ready (1st iter) / prev PV reads of KPt,Vs done
        // stage K^T, V, yns, yds
#pragma unroll
        for (int p = 0; p < 4; p++) {
            int n = p * 16 + ty;
            float4 g = *(const float4*)&Ke[(size_t)(k0 + n) * 1024 + h * 64 + d0];
            KPt[d0 + 0][n] = g.x; KPt[d0 + 1][n] = g.y; KPt[d0 + 2][n] = g.z; KPt[d0 + 3][n] = g.w;
            float4 v = *(const float4*)&Vf[(size_t)(k0 + n) * 1024 + h * 64 + d0];
            *(float4*)&Vs[n][d0] = v;
        }
        if (tid < 64)  yl[tid]       = yns[h * 2048 + k0 + tid];
        else if (tid < 128) ydl[tid - 64] = yds[h * 2048 + k0 + tid - 64];
        __syncthreads();

        // S = Q @ K^T (64x64x64 from LDS)
        float sacc[4][4] = {};
#pragma unroll 8
        for (int k = 0; k < 64; k++) {
            float4 qa = *(const float4*)&Qt[k][m0];
            float4 kb = *(const float4*)&KPt[k][d0];
            sacc[0][0] += qa.x * kb.x; sacc[0][1] += qa.x * kb.y; sacc[0][2] += qa.x * kb.z; sacc[0][3] += qa.x * kb.w;
            sacc[1][0] += qa.y * kb.x; sacc[1][1] += qa.y * kb.y; sacc[1][2] += qa.y * kb.z; sacc[1][3] += qa.y * kb.w;
            sacc[2][0] += qa.z * kb.x; sacc[2][1] += qa.z * kb.y; sacc[2][2] += qa.z * kb.z; sacc[2][3] += qa.z * kb.w;
            sacc[3][0] += qa.w * kb.x; sacc[3][1] += qa.w * kb.y; sacc[3][2] += qa.w * kb.z; sacc[3][3] += qa.w * kb.w;
        }

        // elementwise Poincare score transform (+ causal mask on diagonal tile)
        const bool diag = (jt == qt);
        float s[4][4];
#pragma unroll
        for (int r = 0; r < 4; r++) {
#pragma unroll
            for (int cc = 0; cc < 4; cc++) {
                float yj   = yl[d0 + cc];
                float diff = xi[r] - 2.f * sacc[r][cc] + yj;
                float den  = fmaxf(dxr[r] * ydl[d0 + cc], EPSF);
                float arg  = 1.f + (2.f * c) * diff / den;
                float z    = fmaxf(arg, 1.f + EPSF);
                float dist = __logf(z + sqrtf(z * z - 1.f)) * inv_sc;
                float sv   = -bpos * dist - bias;
                if (diag && (k0 + d0 + cc > q0 + m0 + r)) sv = -3.0e38f;
                s[r][cc] = sv;
            }
        }

        // wave-parallel online softmax (rows spread across tx lanes: bits 0-3)
        float pw[4][4], scalef[4];
#pragma unroll
        for (int r = 0; r < 4; r++) {
            float tm = fmaxf(fmaxf(s[r][0], s[r][1]), fmaxf(s[r][2], s[r][3]));
#pragma unroll
            for (int o = 1; o < 16; o <<= 1) tm = fmaxf(tm, __shfl_xor(tm, o));
            float nm  = fmaxf(mrow[r], tm);
            scalef[r] = __expf(mrow[r] - nm);
            mrow[r]   = nm;
            float rs  = 0.f;
#pragma unroll
            for (int cc = 0; cc < 4; cc++) {
                float p = (s[r][cc] <= -1.0e38f) ? 0.f : __expf(s[r][cc] - nm);
                pw[r][cc] = p;
                rs += p;
            }
#pragma unroll
            for (int o = 1; o < 16; o <<= 1) rs += __shfl_xor(rs, o);
            lrow[r] = lrow[r] * scalef[r] + rs;
#pragma unroll
            for (int cc = 0; cc < 4; cc++) acc[r][cc] *= scalef[r];
        }

        __syncthreads();   // all waves done reading K^T before P^T overwrite
        // write P^T[j][m] (float4 along m)
#pragma unroll
        for (int cc = 0; cc < 4; cc++) {
            float4 p4 = make_float4(pw[0][cc], pw[1][cc], pw[2][cc], pw[3][cc]);
            *(float4*)&KPt[d0 + cc][m0] = p4;
        }
        __syncthreads();

        // acc += P @ V
#pragma unroll 8
        for (int j = 0; j < 64; j++) {
            float4 pa = *(const float4*)&KPt[j][m0];
            float4 vb = *(const float4*)&Vs[j][d0];
            acc[0][0] += pa.x * vb.x; acc[0][1] += pa.x * vb.y; acc[0][2] += pa.x * vb.z; acc[0][3] += pa.x * vb.w;
            acc[1][0] += pa.y * vb.x; acc[1][1] += pa.y * vb.y; acc[1][2] += pa.y * vb.z; acc[1][3] += pa.y * vb.w;
            acc[2][0] += pa.z * vb.x; acc[2][1] += pa.z * vb.y; acc[2][2] += pa.z * vb.z; acc[2][3] += pa.z * vb.w;
            acc[3][0] += pa.w * vb.x; acc[3][1] += pa.w * vb.y; acc[3][2] += pa.w * vb.z; acc[3][3] += pa.w * vb.w;
        }
    }

    // epilogue: t = acc/l; exp_map then log_map
#pragma unroll
    for (int r = 0; r < 4; r++) {
        float rl = 1.f / lrow[r];
        float t[4];
        float n2 = 0.f;
#pragma unroll
        for (int cc = 0; cc < 4; cc++) { t[cc] = acc[r][cc] * rl; n2 += t[cc] * t[cc]; }
#pragma unroll
        for (int o = 1; o < 16; o <<= 1) n2 += __shfl_xor(n2, o);
        float nt   = fmaxf(sqrtf(n2), EPSF);
        float f1   = tanhf(sc * nt) / (sc * nt);
        float ny   = fmaxf(f1 * sqrtf(n2), EPSF);
        float ncl  = fminf(ny, inv_sc - EPSF);
        float coef = atanhf(sc * ncl) / (sc * ny);
        float4 o4;
        o4.x = coef * f1 * t[0]; o4.y = coef * f1 * t[1];
        o4.z = coef * f1 * t[2]; o4.w = coef * f1 * t[3];
        *(float4*)&conc[(size_t)(q0 + m0 + r) * 1024 + h * 64 + d0] = o4;
    }
}

// ---------------- launch ----------------
extern "C" void kernel_launch(void* const* d_in, const int* in_sizes, int n_in,
                              void* d_out, int out_size, void* d_ws, size_t ws_size,
                              hipStream_t stream) {
    const float* x     = (const float*)d_in[0];
    const float* Wq    = (const float*)d_in[1];
    const float* Wk    = (const float*)d_in[2];
    const float* Wv    = (const float*)d_in[3];
    const float* Wo    = (const float*)d_in[4];
    const float* pLogC = (const float*)d_in[5];
    const float* pBeta = (const float*)d_in[6];
    const float* pBias = (const float*)d_in[7];
    float* out = (float*)d_out;

    char* w = (char*)d_ws;
    float* Q    = (float*)(w);
    float* Kf   = (float*)(w + (8u  << 20));
    float* Vf   = (float*)(w + (16u << 20));
    float* conc = (float*)(w + (24u << 20));
    float* xns  = (float*)(w + (32u << 20));
    float* yns  = (float*)(w + (32u << 20) + (1u << 17));
    float* xds  = (float*)(w + (32u << 20) + (2u << 17));
    float* yds  = (float*)(w + (32u << 20) + (3u << 17));

    k_gemm_nt_f32<<<512, 256, 0, stream>>>(x, Wq, Q,  2048, 1024, 1024);
    k_gemm_nt_f32<<<512, 256, 0, stream>>>(x, Wk, Kf, 2048, 1024, 1024);
    k_gemm_nt_f32<<<512, 256, 0, stream>>>(x, Wv, Vf, 2048, 1024, 1024);

    k_expmap<<<8192, 256, 0, stream>>>(Q,  xns, xds, pLogC);
    k_expmap<<<8192, 256, 0, stream>>>(Kf, yns, yds, pLogC);

    k_attn_tiled<<<512, 256, 0, stream>>>(Q, Kf, Vf, xns, xds, yns, yds,
                                          pLogC, pBeta, pBias, conc);

    k_gemm_nt_f32<<<512, 256, 0, stream>>>(conc, Wo, out, 2048, 1024, 1024);
}

// Round 5
// 387.124 us; speedup vs baseline: 11.4419x; 1.6204x over previous
//
#include <hip/hip_runtime.h>
#include <stdint.h>

#define EPSF 1e-5f

typedef float f32x4 __attribute__((ext_vector_type(4)));
typedef short bf16x8 __attribute__((ext_vector_type(8)));   // 8 bf16 in 4 VGPRs (guide §3)

__device__ __forceinline__ float softplus_f(float x) {
    return x > 20.f ? x : log1pf(expf(x));
}

// fp32 -> bf16 RNE (finite inputs)
__device__ __forceinline__ unsigned short f2bf(float f) {
    union { float f; unsigned int u; } v; v.f = f;
    unsigned int r = v.u + 0x7FFFu + ((v.u >> 16) & 1u);
    return (unsigned short)(r >> 16);
}
__device__ __forceinline__ float bf2f(unsigned short u) {
    union { unsigned int i; float f; } v; v.i = ((unsigned int)u) << 16;
    return v.f;
}

// ---------------- convert fp32 -> bf16 ----------------
__global__ __launch_bounds__(256) void k_f2b(const float* __restrict__ in,
                                             unsigned short* __restrict__ out, int n) {
    int i = blockIdx.x * 256 + threadIdx.x;
    int stride = gridDim.x * 256;
    for (; i < n; i += stride) out[i] = f2bf(in[i]);
}

// ---------------- bf16 MFMA GEMM: C[M][N] = A[M][K] * B[N][K]^T ----------------
// A,B bf16 (ushort bits) row-major. OUT_BF16: C bf16 else fp32.
// Tile 128(M) x 64(N) x 32(K); 4 waves in 2x2; wave tile 64x32 = 4x2 frags of 16x16.
// LDS stride 56 shorts (112B): row offsets 16B-aligned, bank pattern 2-way (free).
template <int OUT_BF16>
__global__ __launch_bounds__(256) void k_gemm_mfma(const unsigned short* __restrict__ A,
                                                   const unsigned short* __restrict__ B,
                                                   void* __restrict__ Cv,
                                                   int M, int N, int K) {
    constexpr int LDA = 56;
    __shared__ __align__(16) unsigned short As[128 * LDA];
    __shared__ __align__(16) unsigned short Bs[64 * LDA];
    const int tid  = threadIdx.x;
    const int lane = tid & 63;
    const int w    = tid >> 6;
    const int wr   = w >> 1, wc = w & 1;
    const int fr   = lane & 15;          // A row / B col within fragment
    const int fg   = lane >> 4;          // k-slot group (8 elems)
    const int nbx  = N >> 6;
    const int bx   = blockIdx.x % nbx;
    const int by   = blockIdx.x / nbx;
    const int bm0  = by * 128, bn0 = bx * 64;

    const int srow = tid >> 2;           // 0..63
    const int scol = (tid & 3) * 8;      // 0,8,16,24

    f32x4 acc[4][2] = {};

    for (int kk = 0; kk < K; kk += 32) {
        uint4 a0 = *(const uint4*)&A[(size_t)(bm0 + srow) * K + kk + scol];
        uint4 a1 = *(const uint4*)&A[(size_t)(bm0 + 64 + srow) * K + kk + scol];
        uint4 b0 = *(const uint4*)&B[(size_t)(bn0 + srow) * K + kk + scol];
        *(uint4*)&As[srow * LDA + scol]        = a0;
        *(uint4*)&As[(64 + srow) * LDA + scol] = a1;
        *(uint4*)&Bs[srow * LDA + scol]        = b0;
        __syncthreads();

        bf16x8 av[4], bv[2];
#pragma unroll
        for (int m = 0; m < 4; m++)
            av[m] = *(const bf16x8*)&As[(wr * 64 + m * 16 + fr) * LDA + fg * 8];
#pragma unroll
        for (int n = 0; n < 2; n++)
            bv[n] = *(const bf16x8*)&Bs[(wc * 32 + n * 16 + fr) * LDA + fg * 8];
#pragma unroll
        for (int m = 0; m < 4; m++)
#pragma unroll
            for (int n = 0; n < 2; n++)
                acc[m][n] = __builtin_amdgcn_mfma_f32_16x16x32_bf16(av[m], bv[n], acc[m][n], 0, 0, 0);
        __syncthreads();
    }

    // C/D layout (m89/m91 verified): col = lane&15, row = (lane>>4)*4 + reg
    const int crow0 = bm0 + wr * 64 + fg * 4;
    const int ccol0 = bn0 + wc * 32 + fr;
#pragma unroll
    for (int m = 0; m < 4; m++)
#pragma unroll
        for (int n = 0; n < 2; n++)
#pragma unroll
            for (int r = 0; r < 4; r++) {
                size_t ci = (size_t)(crow0 + m * 16 + r) * N + ccol0 + n * 16;
                if (OUT_BF16) ((unsigned short*)Cv)[ci] = f2bf(acc[m][n][r]);
                else          ((float*)Cv)[ci]          = acc[m][n][r];
            }
}

// ---------------- exp_map (in place, fp32) + ||y||^2 + STABLE (1 - c||y||^2) ----------------
__global__ __launch_bounds__(256) void k_expmap(float* __restrict__ QK,
                                                float* __restrict__ ns,
                                                float* __restrict__ ds,
                                                const float* __restrict__ pLogC) {
    float c  = softplus_f(pLogC[0]);
    float sc = sqrtf(c);
    int gid  = (blockIdx.x * 256 + threadIdx.x) >> 6;
    int lane = threadIdx.x & 63;
    int n = gid >> 4, h = gid & 15;
    size_t idx = (size_t)n * 1024 + h * 64 + lane;
    float v  = QK[idx];
    float n2 = v * v;
#pragma unroll
    for (int o = 1; o < 64; o <<= 1) n2 += __shfl_xor(n2, o);
    float nn = fmaxf(sqrtf(n2), EPSF);
    float u  = sc * nn;
    float e  = __expf(-2.f * u);
    float th = (1.f - e) / (1.f + e);          // tanh(u), stable
    float f  = th / (sc * nn);
    QK[idx]  = f * v;
    if (lane == 0) {
        float xn = f * f * n2;
        ns[h * 2048 + n] = xn;
        float op = 1.f + e;
        float sech2 = 4.f * e / (op * op);     // 1 - tanh^2(u), no cancellation
        ds[h * 2048 + n] = (n2 < 1e-6f) ? (1.f - c * xn) : sech2;
    }
}

// ---------------- tiled flash-style attention (fp32 SIMT; V in bf16; conc out bf16) ----------------
__global__ __launch_bounds__(256) void k_attn_tiled(const float* __restrict__ Qe,
                                                    const float* __restrict__ Ke,
                                                    const unsigned short* __restrict__ Vb,
                                                    const float* __restrict__ xns,
                                                    const float* __restrict__ xds,
                                                    const float* __restrict__ yns,
                                                    const float* __restrict__ yds,
                                                    const float* __restrict__ pLogC,
                                                    const float* __restrict__ pBeta,
                                                    const float* __restrict__ pBias,
                                                    unsigned short* __restrict__ conc) {
    __shared__ float Qt[64][68];    // Q^T tile: [d][m]
    __shared__ float KPt[64][68];   // K^T tile [d][n] during S; P^T [j][m] during PV
    __shared__ float Vs[64][68];    // V tile: [j][d]
    __shared__ float yl[64];
    __shared__ float ydl[64];

    const float c      = softplus_f(pLogC[0]);
    const float sc     = sqrtf(c);
    const float inv_sc = 1.f / sc;
    const float bpos   = softplus_f(pBeta[0]);
    const float bias   = pBias[0];

    const int bid = blockIdx.x;
    const int qt  = 31 - (bid >> 4);   // heavy tiles first (tail-imbalance fix)
    const int h   = bid & 15;
    const int q0  = qt << 6;
    const int tid = threadIdx.x;
    const int tx  = tid & 15, ty = tid >> 4;
    const int m0  = ty * 4;
    const int d0  = tx * 4;

#pragma unroll
    for (int p = 0; p < 4; p++) {
        int m = p * 16 + ty;
        float4 g = *(const float4*)&Qe[(size_t)(q0 + m) * 1024 + h * 64 + d0];
        Qt[d0 + 0][m] = g.x; Qt[d0 + 1][m] = g.y; Qt[d0 + 2][m] = g.z; Qt[d0 + 3][m] = g.w;
    }

    float xi[4], dxr[4], mrow[4], lrow[4];
#pragma unroll
    for (int r = 0; r < 4; r++) {
        xi[r]   = xns[h * 2048 + q0 + m0 + r];
        dxr[r]  = xds[h * 2048 + q0 + m0 + r];
        mrow[r] = -3.0e38f;
        lrow[r] = 0.f;
    }
    float acc[4][4] = {};

    for (int jt = 0; jt <= qt; ++jt) {
        const int k0 = jt << 6;
        __syncthreads();
#pragma unroll
        for (int p = 0; p < 4; p++) {
            int n = p * 16 + ty;
            float4 g = *(const float4*)&Ke[(size_t)(k0 + n) * 1024 + h * 64 + d0];
            KPt[d0 + 0][n] = g.x; KPt[d0 + 1][n] = g.y; KPt[d0 + 2][n] = g.z; KPt[d0 + 3][n] = g.w;
            ushort4 vv = *(const ushort4*)&Vb[(size_t)(k0 + n) * 1024 + h * 64 + d0];
            Vs[n][d0 + 0] = bf2f(vv.x); Vs[n][d0 + 1] = bf2f(vv.y);
            Vs[n][d0 + 2] = bf2f(vv.z); Vs[n][d0 + 3] = bf2f(vv.w);
        }
        if (tid < 64)       yl[tid]        = yns[h * 2048 + k0 + tid];
        else if (tid < 128) ydl[tid - 64]  = yds[h * 2048 + k0 + tid - 64];
        __syncthreads();

        // S = Q @ K^T
        float sacc[4][4] = {};
#pragma unroll 8
        for (int k = 0; k < 64; k++) {
            float4 qa = *(const float4*)&Qt[k][m0];
            float4 kb = *(const float4*)&KPt[k][d0];
            sacc[0][0] += qa.x * kb.x; sacc[0][1] += qa.x * kb.y; sacc[0][2] += qa.x * kb.z; sacc[0][3] += qa.x * kb.w;
            sacc[1][0] += qa.y * kb.x; sacc[1][1] += qa.y * kb.y; sacc[1][2] += qa.y * kb.z; sacc[1][3] += qa.y * kb.w;
            sacc[2][0] += qa.z * kb.x; sacc[2][1] += qa.z * kb.y; sacc[2][2] += qa.z * kb.z; sacc[2][3] += qa.z * kb.w;
            sacc[3][0] += qa.w * kb.x; sacc[3][1] += qa.w * kb.y; sacc[3][2] += qa.w * kb.z; sacc[3][3] += qa.w * kb.w;
        }

        const bool diag = (jt == qt);
        float s[4][4];
#pragma unroll
        for (int r = 0; r < 4; r++) {
#pragma unroll
            for (int cc = 0; cc < 4; cc++) {
                float yj   = yl[d0 + cc];
                float diff = xi[r] - 2.f * sacc[r][cc] + yj;
                float den  = fmaxf(dxr[r] * ydl[d0 + cc], EPSF);
                float arg  = 1.f + (2.f * c) * diff / den;
                float z    = fmaxf(arg, 1.f + EPSF);
                float dist = __logf(z + sqrtf(z * z - 1.f)) * inv_sc;
                float sv   = -bpos * dist - bias;
                if (diag && (k0 + d0 + cc > q0 + m0 + r)) sv = -3.0e38f;
                s[r][cc] = sv;
            }
        }

        float pw[4][4], scalef[4];
#pragma unroll
        for (int r = 0; r < 4; r++) {
            float tm = fmaxf(fmaxf(s[r][0], s[r][1]), fmaxf(s[r][2], s[r][3]));
#pragma unroll
            for (int o = 1; o < 16; o <<= 1) tm = fmaxf(tm, __shfl_xor(tm, o));
            float nm  = fmaxf(mrow[r], tm);
            scalef[r] = __expf(mrow[r] - nm);
            mrow[r]   = nm;
            float rs  = 0.f;
#pragma unroll
            for (int cc = 0; cc < 4; cc++) {
                float p = (s[r][cc] <= -1.0e38f) ? 0.f : __expf(s[r][cc] - nm);
                pw[r][cc] = p;
                rs += p;
            }
#pragma unroll
            for (int o = 1; o < 16; o <<= 1) rs += __shfl_xor(rs, o);
            lrow[r] = lrow[r] * scalef[r] + rs;
#pragma unroll
            for (int cc = 0; cc < 4; cc++) acc[r][cc] *= scalef[r];
        }

        __syncthreads();
#pragma unroll
        for (int cc = 0; cc < 4; cc++) {
            float4 p4 = make_float4(pw[0][cc], pw[1][cc], pw[2][cc], pw[3][cc]);
            *(float4*)&KPt[d0 + cc][m0] = p4;
        }
        __syncthreads();

#pragma unroll 8
        for (int j = 0; j < 64; j++) {
            float4 pa = *(const float4*)&KPt[j][m0];
            float4 vb = *(const float4*)&Vs[j][d0];
            acc[0][0] += pa.x * vb.x; acc[0][1] += pa.x * vb.y; acc[0][2] += pa.x * vb.z; acc[0][3] += pa.x * vb.w;
            acc[1][0] += pa.y * vb.x; acc[1][1] += pa.y * vb.y; acc[1][2] += pa.y * vb.z; acc[1][3] += pa.y * vb.w;
            acc[2][0] += pa.z * vb.x; acc[2][1] += pa.z * vb.y; acc[2][2] += pa.z * vb.z; acc[2][3] += pa.z * vb.w;
            acc[3][0] += pa.w * vb.x; acc[3][1] += pa.w * vb.y; acc[3][2] += pa.w * vb.z; acc[3][3] += pa.w * vb.w;
        }
    }

    // epilogue: t = acc/l; exp_map then log_map; write bf16
#pragma unroll
    for (int r = 0; r < 4; r++) {
        float rl = 1.f / lrow[r];
        float t[4];
        float n2 = 0.f;
#pragma unroll
        for (int cc = 0; cc < 4; cc++) { t[cc] = acc[r][cc] * rl; n2 += t[cc] * t[cc]; }
#pragma unroll
        for (int o = 1; o < 16; o <<= 1) n2 += __shfl_xor(n2, o);
        float nt   = fmaxf(sqrtf(n2), EPSF);
        float f1   = tanhf(sc * nt) / (sc * nt);
        float ny   = fmaxf(f1 * sqrtf(n2), EPSF);
        float ncl  = fminf(ny, inv_sc - EPSF);
        float coef = atanhf(sc * ncl) / (sc * ny);
        ushort4 o4;
        o4.x = f2bf(coef * f1 * t[0]); o4.y = f2bf(coef * f1 * t[1]);
        o4.z = f2bf(coef * f1 * t[2]); o4.w = f2bf(coef * f1 * t[3]);
        *(ushort4*)&conc[(size_t)(q0 + m0 + r) * 1024 + h * 64 + d0] = o4;
    }
}

// ---------------- launch ----------------
// ws layout (30.5 MB total, stream-ordered reuse):
//   0-4   MB: xb (x bf16)
//   4-8   MB: wqb(2)+wkb(2)  -> reused as concb (bf16, 4 MB) after Q/K GEMMs
//   8-10  MB: wvb            -> reused as wob after V GEMM
//   10-18 MB: Q fp32
//   18-26 MB: Kf fp32
//   26-30 MB: Vb bf16
//   30-30.5MB: xns/yns/xds/yds (4 x 128 KB)
extern "C" void kernel_launch(void* const* d_in, const int* in_sizes, int n_in,
                              void* d_out, int out_size, void* d_ws, size_t ws_size,
                              hipStream_t stream) {
    const float* x     = (const float*)d_in[0];
    const float* Wq    = (const float*)d_in[1];
    const float* Wk    = (const float*)d_in[2];
    const float* Wv    = (const float*)d_in[3];
    const float* Wo    = (const float*)d_in[4];
    const float* pLogC = (const float*)d_in[5];
    const float* pBeta = (const float*)d_in[6];
    const float* pBias = (const float*)d_in[7];
    float* out = (float*)d_out;

    char* w = (char*)d_ws;
    unsigned short* xb    = (unsigned short*)(w);
    unsigned short* wqb   = (unsigned short*)(w + (4u << 20));
    unsigned short* wkb   = (unsigned short*)(w + (6u << 20));
    unsigned short* wvb   = (unsigned short*)(w + (8u << 20));
    unsigned short* concb = (unsigned short*)(w + (4u << 20));   // reuse wqb+wkb
    unsigned short* wob   = (unsigned short*)(w + (8u << 20));   // reuse wvb
    float*          Q     = (float*)(w + (10u << 20));
    float*          Kf    = (float*)(w + (18u << 20));
    unsigned short* Vb    = (unsigned short*)(w + (26u << 20));
    float*          xns   = (float*)(w + (30u << 20));
    float*          yns   = (float*)(w + (30u << 20) + (1u << 17));
    float*          xds   = (float*)(w + (30u << 20) + (2u << 17));
    float*          yds   = (float*)(w + (30u << 20) + (3u << 17));

    k_f2b<<<2048, 256, 0, stream>>>(x,  xb,  2048 * 1024);
    k_f2b<<<1024, 256, 0, stream>>>(Wq, wqb, 1024 * 1024);
    k_f2b<<<1024, 256, 0, stream>>>(Wk, wkb, 1024 * 1024);
    k_f2b<<<1024, 256, 0, stream>>>(Wv, wvb, 1024 * 1024);

    k_gemm_mfma<0><<<256, 256, 0, stream>>>(xb, wqb, Q,  2048, 1024, 1024);
    k_gemm_mfma<0><<<256, 256, 0, stream>>>(xb, wkb, Kf, 2048, 1024, 1024);
    k_gemm_mfma<1><<<256, 256, 0, stream>>>(xb, wvb, Vb, 2048, 1024, 1024);

    k_f2b<<<1024, 256, 0, stream>>>(Wo, wob, 1024 * 1024);   // after V GEMM (reuses wvb)

    k_expmap<<<8192, 256, 0, stream>>>(Q,  xns, xds, pLogC);
    k_expmap<<<8192, 256, 0, stream>>>(Kf, yns, yds, pLogC);

    k_attn_tiled<<<512, 256, 0, stream>>>(Q, Kf, Vb, xns, xds, yns, yds,
                                          pLogC, pBeta, pBias, concb);

    k_gemm_mfma<0><<<256, 256, 0, stream>>>(concb, wob, out, 2048, 1024, 1024);
}

// Round 6
// 259.629 us; speedup vs baseline: 17.0606x; 1.4911x over previous
//
#include <hip/hip_runtime.h>
#include <stdint.h>

#define EPSF 1e-5f

typedef float f32x4 __attribute__((ext_vector_type(4)));
typedef short bf16x8 __attribute__((ext_vector_type(8)));   // 8 bf16 in 4 VGPRs

__device__ __forceinline__ float softplus_f(float x) {
    return x > 20.f ? x : log1pf(expf(x));
}

// fp32 -> bf16 RNE (finite inputs)
__device__ __forceinline__ unsigned short f2bf(float f) {
    union { float f; unsigned int u; } v; v.f = f;
    unsigned int r = v.u + 0x7FFFu + ((v.u >> 16) & 1u);
    return (unsigned short)(r >> 16);
}
__device__ __forceinline__ float bf2f(unsigned short u) {
    union { unsigned int i; float f; } v; v.i = ((unsigned int)u) << 16;
    return v.f;
}

// ---------------- convert fp32 -> bf16 ----------------
__global__ __launch_bounds__(256) void k_f2b(const float* __restrict__ in,
                                             unsigned short* __restrict__ out, int n) {
    int i = blockIdx.x * 256 + threadIdx.x;
    int stride = gridDim.x * 256;
    for (; i < n; i += stride) out[i] = f2bf(in[i]);
}

// ---------------- bf16 MFMA GEMM: C[M][N] = A[M][K] * B[N][K]^T ----------------
// (verified round 5) Tile 128x64x32; 4 waves 2x2; LDS stride 56 shorts.
template <int OUT_BF16>
__global__ __launch_bounds__(256) void k_gemm_mfma(const unsigned short* __restrict__ A,
                                                   const unsigned short* __restrict__ B,
                                                   void* __restrict__ Cv,
                                                   int M, int N, int K) {
    constexpr int LDA = 56;
    __shared__ __align__(16) unsigned short As[128 * LDA];
    __shared__ __align__(16) unsigned short Bs[64 * LDA];
    const int tid  = threadIdx.x;
    const int lane = tid & 63;
    const int w    = tid >> 6;
    const int wr   = w >> 1, wc = w & 1;
    const int fr   = lane & 15;
    const int fg   = lane >> 4;
    const int nbx  = N >> 6;
    const int bx   = blockIdx.x % nbx;
    const int by   = blockIdx.x / nbx;
    const int bm0  = by * 128, bn0 = bx * 64;

    const int srow = tid >> 2;
    const int scol = (tid & 3) * 8;

    f32x4 acc[4][2] = {};

    for (int kk = 0; kk < K; kk += 32) {
        uint4 a0 = *(const uint4*)&A[(size_t)(bm0 + srow) * K + kk + scol];
        uint4 a1 = *(const uint4*)&A[(size_t)(bm0 + 64 + srow) * K + kk + scol];
        uint4 b0 = *(const uint4*)&B[(size_t)(bn0 + srow) * K + kk + scol];
        *(uint4*)&As[srow * LDA + scol]        = a0;
        *(uint4*)&As[(64 + srow) * LDA + scol] = a1;
        *(uint4*)&Bs[srow * LDA + scol]        = b0;
        __syncthreads();

        bf16x8 av[4], bv[2];
#pragma unroll
        for (int m = 0; m < 4; m++)
            av[m] = *(const bf16x8*)&As[(wr * 64 + m * 16 + fr) * LDA + fg * 8];
#pragma unroll
        for (int n = 0; n < 2; n++)
            bv[n] = *(const bf16x8*)&Bs[(wc * 32 + n * 16 + fr) * LDA + fg * 8];
#pragma unroll
        for (int m = 0; m < 4; m++)
#pragma unroll
            for (int n = 0; n < 2; n++)
                acc[m][n] = __builtin_amdgcn_mfma_f32_16x16x32_bf16(av[m], bv[n], acc[m][n], 0, 0, 0);
        __syncthreads();
    }

    const int crow0 = bm0 + wr * 64 + fg * 4;
    const int ccol0 = bn0 + wc * 32 + fr;
#pragma unroll
    for (int m = 0; m < 4; m++)
#pragma unroll
        for (int n = 0; n < 2; n++)
#pragma unroll
            for (int r = 0; r < 4; r++) {
                size_t ci = (size_t)(crow0 + m * 16 + r) * N + ccol0 + n * 16;
                if (OUT_BF16) ((unsigned short*)Cv)[ci] = f2bf(acc[m][n][r]);
                else          ((float*)Cv)[ci]          = acc[m][n][r];
            }
}

// ---------------- exp_map in place on bf16 + ||y||^2 + STABLE (1 - c||y||^2) ----------------
// QK bf16 [n][h*64+d]; ns/ds [h*2048+n]. sech^2 via exp(-2u): no cancellation.
__global__ __launch_bounds__(256) void k_expmap_b(unsigned short* __restrict__ QK,
                                                  float* __restrict__ ns,
                                                  float* __restrict__ ds,
                                                  const float* __restrict__ pLogC) {
    float c  = softplus_f(pLogC[0]);
    float sc = sqrtf(c);
    int gid  = (blockIdx.x * 256 + threadIdx.x) >> 6;
    int lane = threadIdx.x & 63;
    int n = gid >> 4, h = gid & 15;
    size_t idx = (size_t)n * 1024 + h * 64 + lane;
    float v  = bf2f(QK[idx]);
    float n2 = v * v;
#pragma unroll
    for (int o = 1; o < 64; o <<= 1) n2 += __shfl_xor(n2, o);
    float nn = fmaxf(sqrtf(n2), EPSF);
    float u  = sc * nn;
    float e  = __expf(-2.f * u);
    float th = (1.f - e) / (1.f + e);          // tanh(u), stable
    float f  = th / (sc * nn);
    QK[idx]  = f2bf(f * v);
    if (lane == 0) {
        float xn = f * f * n2;
        ns[h * 2048 + n] = xn;
        float op = 1.f + e;
        float sech2 = 4.f * e / (op * op);     // 1 - tanh^2(u), no cancellation
        ds[h * 2048 + n] = (n2 < 1e-6f) ? (1.f - c * xn) : sech2;
    }
}

// ---------------- MFMA flash attention ----------------
// Block = (head h, 64 q-rows); 4 waves, wave w owns q-rows [w*16, w*16+16).
// LDS tiles bf16 [64][72] (144B rows: 16B-aligned, b128 reads 2-way-free banks).
// Fragment conventions identical to the round-5-verified GEMM:
//   A/B frag: row/col = lane&15, k = (lane>>4)*8 ; D: col = lane&15, row = (lane>>4)*4+reg.
__global__ __launch_bounds__(256) void k_attn_mfma(const unsigned short* __restrict__ Qb,
                                                   const unsigned short* __restrict__ Kb,
                                                   const unsigned short* __restrict__ Vb,
                                                   const float* __restrict__ xns,
                                                   const float* __restrict__ xds,
                                                   const float* __restrict__ yns,
                                                   const float* __restrict__ yds,
                                                   const float* __restrict__ pLogC,
                                                   const float* __restrict__ pBeta,
                                                   const float* __restrict__ pBias,
                                                   unsigned short* __restrict__ conc) {
    __shared__ __align__(16) unsigned short Qs[64][72];  // Q rows [q][k]
    __shared__ __align__(16) unsigned short Ks[64][72];  // K rows [key][k]
    __shared__ __align__(16) unsigned short Vt[64][72];  // V transposed [d][key]
    __shared__ __align__(16) unsigned short Ps[64][72];  // P rows [q][key] (wave-private rows)
    __shared__ float yl[64], ydl[64];

    const float c      = softplus_f(pLogC[0]);
    const float sc     = sqrtf(c);
    const float inv_sc = 1.f / sc;
    const float bpos   = softplus_f(pBeta[0]);
    const float bias   = pBias[0];

    const int bid  = blockIdx.x;
    const int qt   = 31 - (bid >> 4);   // heavy tiles first
    const int h    = bid & 15;
    const int q0   = qt << 6;
    const int tid  = threadIdx.x;
    const int lane = tid & 63;
    const int w    = tid >> 6;
    const int wq0  = w * 16;            // wave's q-row offset within tile
    const int fr   = lane & 15;
    const int fg   = lane >> 4;

    // stage Q tile (64 rows x 64 k, bf16): 512 x 16B
#pragma unroll
    for (int p = 0; p < 2; p++) {
        int idx = tid + p * 256;
        int r = idx >> 3, cb = (idx & 7) * 8;
        *(uint4*)&Qs[r][cb] = *(const uint4*)&Qb[(size_t)(q0 + r) * 1024 + h * 64 + cb];
    }

    float xi[4], dxr[4], mrow[4], lrow[4];
#pragma unroll
    for (int r = 0; r < 4; r++) {
        int row = q0 + wq0 + fg * 4 + r;
        xi[r]   = xns[h * 2048 + row];
        dxr[r]  = xds[h * 2048 + row];
        mrow[r] = -3.0e38f;
        lrow[r] = 0.f;
    }
    f32x4 acc[4] = {};   // [d-tile], reg r = row fg*4+r

    for (int jt = 0; jt <= qt; ++jt) {
        const int k0 = jt << 6;
        __syncthreads();   // prev iter reads of Ks/Vt done; Qs staged (1st iter)
        // stage K rows
#pragma unroll
        for (int p = 0; p < 2; p++) {
            int idx = tid + p * 256;
            int r = idx >> 3, cb = (idx & 7) * 8;
            *(uint4*)&Ks[r][cb] = *(const uint4*)&Kb[(size_t)(k0 + r) * 1024 + h * 64 + cb];
        }
        // stage V transposed: Vt[d][key]
#pragma unroll
        for (int p = 0; p < 4; p++) {
            int idx = tid + p * 256;
            int n = idx >> 4, dg = (idx & 15) * 4;
            ushort4 v = *(const ushort4*)&Vb[(size_t)(k0 + n) * 1024 + h * 64 + dg];
            Vt[dg + 0][n] = v.x; Vt[dg + 1][n] = v.y;
            Vt[dg + 2][n] = v.z; Vt[dg + 3][n] = v.w;
        }
        if (tid < 64)       yl[tid]       = yns[h * 2048 + k0 + tid];
        else if (tid < 128) ydl[tid - 64] = yds[h * 2048 + k0 + tid - 64];
        __syncthreads();

        // ---- S = Q K^T via MFMA: wave rows [wq0,wq0+16) x 64 cols ----
        bf16x8 qa0 = *(const bf16x8*)&Qs[wq0 + fr][fg * 8];
        bf16x8 qa1 = *(const bf16x8*)&Qs[wq0 + fr][32 + fg * 8];
        f32x4 sacc[4] = {};
#pragma unroll
        for (int tn = 0; tn < 4; tn++) {
            bf16x8 kb0 = *(const bf16x8*)&Ks[tn * 16 + fr][fg * 8];
            bf16x8 kb1 = *(const bf16x8*)&Ks[tn * 16 + fr][32 + fg * 8];
            sacc[tn] = __builtin_amdgcn_mfma_f32_16x16x32_bf16(qa0, kb0, sacc[tn], 0, 0, 0);
            sacc[tn] = __builtin_amdgcn_mfma_f32_16x16x32_bf16(qa1, kb1, sacc[tn], 0, 0, 0);
        }

        // ---- Poincare score transform (D layout: col=tn*16+fr, row=fg*4+r) ----
        const bool diag = (jt == qt);
        float s[4][4];
#pragma unroll
        for (int tn = 0; tn < 4; tn++) {
            float yj  = yl[tn * 16 + fr];
            float dyj = ydl[tn * 16 + fr];
#pragma unroll
            for (int r = 0; r < 4; r++) {
                float diff = xi[r] - 2.f * sacc[tn][r] + yj;
                float den  = fmaxf(dxr[r] * dyj, EPSF);
                float arg  = 1.f + (2.f * c) * diff / den;
                float z    = fmaxf(arg, 1.f + EPSF);
                float dist = __logf(z + sqrtf(z * z - 1.f)) * inv_sc;
                float sv   = -bpos * dist - bias;
                if (diag && (k0 + tn * 16 + fr > q0 + wq0 + fg * 4 + r)) sv = -3.0e38f;
                s[tn][r] = sv;
            }
        }

        // ---- online softmax per row (reduce over tn + lanes bits 0-3) ----
        float pw[4][4];
#pragma unroll
        for (int r = 0; r < 4; r++) {
            float tm = fmaxf(fmaxf(s[0][r], s[1][r]), fmaxf(s[2][r], s[3][r]));
#pragma unroll
            for (int o = 1; o < 16; o <<= 1) tm = fmaxf(tm, __shfl_xor(tm, o));
            float nm = fmaxf(mrow[r], tm);
            float scalef = __expf(mrow[r] - nm);
            mrow[r] = nm;
            float rs = 0.f;
#pragma unroll
            for (int tn = 0; tn < 4; tn++) {
                float p = (s[tn][r] <= -1.0e38f) ? 0.f : __expf(s[tn][r] - nm);
                pw[tn][r] = p;
                rs += p;
            }
#pragma unroll
            for (int o = 1; o < 16; o <<= 1) rs += __shfl_xor(rs, o);
            lrow[r] = lrow[r] * scalef + rs;
#pragma unroll
            for (int tn = 0; tn < 4; tn++) acc[tn][r] *= scalef;
        }

        // ---- write P to wave-private Ps rows (no barrier needed: same-wave RAW) ----
#pragma unroll
        for (int tn = 0; tn < 4; tn++)
#pragma unroll
            for (int r = 0; r < 4; r++)
                Ps[wq0 + fg * 4 + r][tn * 16 + fr] = f2bf(pw[tn][r]);

        // ---- acc += P V via MFMA ----
        bf16x8 pa0 = *(const bf16x8*)&Ps[wq0 + fr][fg * 8];
        bf16x8 pa1 = *(const bf16x8*)&Ps[wq0 + fr][32 + fg * 8];
#pragma unroll
        for (int tn = 0; tn < 4; tn++) {
            bf16x8 vb0 = *(const bf16x8*)&Vt[tn * 16 + fr][fg * 8];
            bf16x8 vb1 = *(const bf16x8*)&Vt[tn * 16 + fr][32 + fg * 8];
            acc[tn] = __builtin_amdgcn_mfma_f32_16x16x32_bf16(pa0, vb0, acc[tn], 0, 0, 0);
            acc[tn] = __builtin_amdgcn_mfma_f32_16x16x32_bf16(pa1, vb1, acc[tn], 0, 0, 0);
        }
    }

    // ---- epilogue: normalize, exp_map then log_map, write bf16 ----
#pragma unroll
    for (int r = 0; r < 4; r++) {
        float rl = 1.f / lrow[r];
        float t[4];
        float n2 = 0.f;
#pragma unroll
        for (int tn = 0; tn < 4; tn++) { t[tn] = acc[tn][r] * rl; n2 += t[tn] * t[tn]; }
#pragma unroll
        for (int o = 1; o < 16; o <<= 1) n2 += __shfl_xor(n2, o);
        float nt   = fmaxf(sqrtf(n2), EPSF);
        float f1   = tanhf(sc * nt) / (sc * nt);
        float ny   = fmaxf(f1 * sqrtf(n2), EPSF);
        float ncl  = fminf(ny, inv_sc - EPSF);
        float coef = atanhf(sc * ncl) / (sc * ny);
        int row = q0 + wq0 + fg * 4 + r;
#pragma unroll
        for (int tn = 0; tn < 4; tn++)
            conc[(size_t)row * 1024 + h * 64 + tn * 16 + fr] = f2bf(coef * f1 * t[tn]);
    }
}

// ---------------- launch ----------------
// ws layout (28.5 MB):
//   0-4: xb | 4-6: wqb | 6-8: wkb | 8-10: wvb | 10-12: wob
//   12-16: Qtb bf16 | 16-20: Ktb bf16 | 20-24: Vb bf16 | 24-28: concb bf16
//   28-28.5: xns/yns/xds/yds (4 x 128 KB)
extern "C" void kernel_launch(void* const* d_in, const int* in_sizes, int n_in,
                              void* d_out, int out_size, void* d_ws, size_t ws_size,
                              hipStream_t stream) {
    const float* x     = (const float*)d_in[0];
    const float* Wq    = (const float*)d_in[1];
    const float* Wk    = (const float*)d_in[2];
    const float* Wv    = (const float*)d_in[3];
    const float* Wo    = (const float*)d_in[4];
    const float* pLogC = (const float*)d_in[5];
    const float* pBeta = (const float*)d_in[6];
    const float* pBias = (const float*)d_in[7];
    float* out = (float*)d_out;

    char* w = (char*)d_ws;
    unsigned short* xb    = (unsigned short*)(w);
    unsigned short* wqb   = (unsigned short*)(w + (4u  << 20));
    unsigned short* wkb   = (unsigned short*)(w + (6u  << 20));
    unsigned short* wvb   = (unsigned short*)(w + (8u  << 20));
    unsigned short* wob   = (unsigned short*)(w + (10u << 20));
    unsigned short* Qtb   = (unsigned short*)(w + (12u << 20));
    unsigned short* Ktb   = (unsigned short*)(w + (16u << 20));
    unsigned short* Vb    = (unsigned short*)(w + (20u << 20));
    unsigned short* concb = (unsigned short*)(w + (24u << 20));
    float*          xns   = (float*)(w + (28u << 20));
    float*          yns   = (float*)(w + (28u << 20) + (1u << 17));
    float*          xds   = (float*)(w + (28u << 20) + (2u << 17));
    float*          yds   = (float*)(w + (28u << 20) + (3u << 17));

    k_f2b<<<2048, 256, 0, stream>>>(x,  xb,  2048 * 1024);
    k_f2b<<<1024, 256, 0, stream>>>(Wq, wqb, 1024 * 1024);
    k_f2b<<<1024, 256, 0, stream>>>(Wk, wkb, 1024 * 1024);
    k_f2b<<<1024, 256, 0, stream>>>(Wv, wvb, 1024 * 1024);
    k_f2b<<<1024, 256, 0, stream>>>(Wo, wob, 1024 * 1024);

    k_gemm_mfma<1><<<256, 256, 0, stream>>>(xb, wqb, Qtb, 2048, 1024, 1024);
    k_gemm_mfma<1><<<256, 256, 0, stream>>>(xb, wkb, Ktb, 2048, 1024, 1024);
    k_gemm_mfma<1><<<256, 256, 0, stream>>>(xb, wvb, Vb,  2048, 1024, 1024);

    k_expmap_b<<<8192, 256, 0, stream>>>(Qtb, xns, xds, pLogC);
    k_expmap_b<<<8192, 256, 0, stream>>>(Ktb, yns, yds, pLogC);

    k_attn_mfma<<<512, 256, 0, stream>>>(Qtb, Ktb, Vb, xns, xds, yns, yds,
                                         pLogC, pBeta, pBias, concb);

    k_gemm_mfma<0><<<256, 256, 0, stream>>>(concb, wob, out, 2048, 1024, 1024);
}

// Round 7
// 240.781 us; speedup vs baseline: 18.3960x; 1.0783x over previous
//
#include <hip/hip_runtime.h>
#include <stdint.h>

#define EPSF 1e-5f

typedef float f32x4 __attribute__((ext_vector_type(4)));
typedef short bf16x8 __attribute__((ext_vector_type(8)));   // 8 bf16 in 4 VGPRs

__device__ __forceinline__ float softplus_f(float x) {
    return x > 20.f ? x : log1pf(expf(x));
}

// fp32 -> bf16 RNE (finite inputs)
__device__ __forceinline__ unsigned short f2bf(float f) {
    union { float f; unsigned int u; } v; v.f = f;
    unsigned int r = v.u + 0x7FFFu + ((v.u >> 16) & 1u);
    return (unsigned short)(r >> 16);
}
__device__ __forceinline__ float bf2f(unsigned short u) {
    union { unsigned int i; float f; } v; v.i = ((unsigned int)u) << 16;
    return v.f;
}

// ---------------- convert fp32 -> bf16 ----------------
__global__ __launch_bounds__(256) void k_f2b(const float* __restrict__ in,
                                             unsigned short* __restrict__ out, int n) {
    int i = blockIdx.x * 256 + threadIdx.x;
    int stride = gridDim.x * 256;
    for (; i < n; i += stride) out[i] = f2bf(in[i]);
}

// fused 4-weight convert (one launch instead of four)
__global__ __launch_bounds__(256) void k_f2bw(const float* __restrict__ W0, const float* __restrict__ W1,
                                              const float* __restrict__ W2, const float* __restrict__ W3,
                                              unsigned short* __restrict__ o0, unsigned short* __restrict__ o1,
                                              unsigned short* __restrict__ o2, unsigned short* __restrict__ o3) {
    int i = blockIdx.x * 256 + threadIdx.x;
    int stride = gridDim.x * 256;
    for (; i < 4 * 1048576; i += stride) {
        int sel = i >> 20, off = i & 1048575;
        const float* src = sel == 0 ? W0 : sel == 1 ? W1 : sel == 2 ? W2 : W3;
        unsigned short* dst = sel == 0 ? o0 : sel == 1 ? o1 : sel == 2 ? o2 : o3;
        dst[off] = f2bf(src[off]);
    }
}

// ---------------- bf16 MFMA GEMM: C[M][N] = A[M][K] * B[N][K]^T ----------------
// (verified round 5/6) Tile 128x64x32; 4 waves 2x2; LDS stride 56 shorts.
template <int OUT_BF16>
__global__ __launch_bounds__(256) void k_gemm_mfma(const unsigned short* __restrict__ A,
                                                   const unsigned short* __restrict__ B,
                                                   void* __restrict__ Cv,
                                                   int M, int N, int K) {
    constexpr int LDA = 56;
    __shared__ __align__(16) unsigned short As[128 * LDA];
    __shared__ __align__(16) unsigned short Bs[64 * LDA];
    const int tid  = threadIdx.x;
    const int lane = tid & 63;
    const int w    = tid >> 6;
    const int wr   = w >> 1, wc = w & 1;
    const int fr   = lane & 15;
    const int fg   = lane >> 4;
    const int nbx  = N >> 6;
    const int bx   = blockIdx.x % nbx;
    const int by   = blockIdx.x / nbx;
    const int bm0  = by * 128, bn0 = bx * 64;

    const int srow = tid >> 2;
    const int scol = (tid & 3) * 8;

    f32x4 acc[4][2] = {};

    for (int kk = 0; kk < K; kk += 32) {
        uint4 a0 = *(const uint4*)&A[(size_t)(bm0 + srow) * K + kk + scol];
        uint4 a1 = *(const uint4*)&A[(size_t)(bm0 + 64 + srow) * K + kk + scol];
        uint4 b0 = *(const uint4*)&B[(size_t)(bn0 + srow) * K + kk + scol];
        *(uint4*)&As[srow * LDA + scol]        = a0;
        *(uint4*)&As[(64 + srow) * LDA + scol] = a1;
        *(uint4*)&Bs[srow * LDA + scol]        = b0;
        __syncthreads();

        bf16x8 av[4], bv[2];
#pragma unroll
        for (int m = 0; m < 4; m++)
            av[m] = *(const bf16x8*)&As[(wr * 64 + m * 16 + fr) * LDA + fg * 8];
#pragma unroll
        for (int n = 0; n < 2; n++)
            bv[n] = *(const bf16x8*)&Bs[(wc * 32 + n * 16 + fr) * LDA + fg * 8];
#pragma unroll
        for (int m = 0; m < 4; m++)
#pragma unroll
            for (int n = 0; n < 2; n++)
                acc[m][n] = __builtin_amdgcn_mfma_f32_16x16x32_bf16(av[m], bv[n], acc[m][n], 0, 0, 0);
        __syncthreads();
    }

    const int crow0 = bm0 + wr * 64 + fg * 4;
    const int ccol0 = bn0 + wc * 32 + fr;
#pragma unroll
    for (int m = 0; m < 4; m++)
#pragma unroll
        for (int n = 0; n < 2; n++)
#pragma unroll
            for (int r = 0; r < 4; r++) {
                size_t ci = (size_t)(crow0 + m * 16 + r) * N + ccol0 + n * 16;
                if (OUT_BF16) ((unsigned short*)Cv)[ci] = f2bf(acc[m][n][r]);
                else          ((float*)Cv)[ci]          = acc[m][n][r];
            }
}

// ---------------- V transpose per head: Vb[n][h*64+d] -> Vtg[(h*64+d)][n] ----------------
__global__ __launch_bounds__(256) void k_vt(const unsigned short* __restrict__ Vb,
                                            unsigned short* __restrict__ Vtg) {
    __shared__ unsigned short T[64][72];
    const int b = blockIdx.x;
    const int h = b & 15;
    const int n0 = (b >> 4) << 6;
    const int tid = threadIdx.x;
#pragma unroll
    for (int p = 0; p < 2; p++) {
        int idx = tid + p * 256;
        int r = idx >> 3, cb = (idx & 7) * 8;
        *(uint4*)&T[r][cb] = *(const uint4*)&Vb[(size_t)(n0 + r) * 1024 + h * 64 + cb];
    }
    __syncthreads();
#pragma unroll
    for (int p = 0; p < 2; p++) {
        int idx = tid + p * 256;
        int d = idx >> 3, nb = (idx & 7) * 8;
        bf16x8 tv;
#pragma unroll
        for (int j = 0; j < 8; j++) tv[j] = (short)T[nb + j][d];
        *(bf16x8*)&Vtg[(size_t)(h * 64 + d) * 2048 + n0 + nb] = tv;
    }
}

// ---------------- exp_map in place on bf16 + ||y||^2 + STABLE (1 - c||y||^2) ----------------
__global__ __launch_bounds__(256) void k_expmap_b(unsigned short* __restrict__ QK,
                                                  float* __restrict__ ns,
                                                  float* __restrict__ ds,
                                                  const float* __restrict__ pLogC) {
    float c  = softplus_f(pLogC[0]);
    float sc = sqrtf(c);
    int gid  = (blockIdx.x * 256 + threadIdx.x) >> 6;
    int lane = threadIdx.x & 63;
    int n = gid >> 4, h = gid & 15;
    size_t idx = (size_t)n * 1024 + h * 64 + lane;
    float v  = bf2f(QK[idx]);
    float n2 = v * v;
#pragma unroll
    for (int o = 1; o < 64; o <<= 1) n2 += __shfl_xor(n2, o);
    float nn = fmaxf(sqrtf(n2), EPSF);
    float u  = sc * nn;
    float e  = __expf(-2.f * u);
    float th = (1.f - e) / (1.f + e);          // tanh(u), stable
    float f  = th / (sc * nn);
    QK[idx]  = f2bf(f * v);
    if (lane == 0) {
        float xn = f * f * n2;
        ns[h * 2048 + n] = xn;
        float op = 1.f + e;
        float sech2 = 4.f * e / (op * op);     // 1 - tanh^2(u), no cancellation
        ds[h * 2048 + n] = (n2 < 1e-6f) ? (1.f - c * xn) : sech2;
    }
}

// ---------------- MFMA flash attention, KV-split partials ----------------
// Grid = 1280 blocks. block b: h = b/80, t = b%80 -> (qt, ci); chunk = kv-tiles
// [ci*8, min(ci*8+8, qt+1)). slot index == b (verified closed-form prefix).
// Per-tile math/layouts identical to the round-6-verified kernel; V staged from
// the pre-transposed Vtg (coalesced rows, no LDS scatter).
// Partials: Og[slot][row][64] bf16 (unnormalized O), ml[slot][row][{m,l}] fp32.
__global__ __launch_bounds__(256) void k_attn_part(const unsigned short* __restrict__ Qb,
                                                   const unsigned short* __restrict__ Kb,
                                                   const unsigned short* __restrict__ Vtg,
                                                   const float* __restrict__ xns,
                                                   const float* __restrict__ xds,
                                                   const float* __restrict__ yns,
                                                   const float* __restrict__ yds,
                                                   const float* __restrict__ pLogC,
                                                   const float* __restrict__ pBeta,
                                                   const float* __restrict__ pBias,
                                                   unsigned short* __restrict__ Og,
                                                   float* __restrict__ ml) {
    __shared__ __align__(16) unsigned short Qs[64][72];  // Q rows [q][k]
    __shared__ __align__(16) unsigned short Ks[64][72];  // K rows [key][k]
    __shared__ __align__(16) unsigned short Vt[64][72];  // V^T rows [d][key]
    __shared__ __align__(16) unsigned short Ps[64][72];  // P rows [q][key] (wave-private)
    __shared__ float yl[64], ydl[64];

    const float c      = softplus_f(pLogC[0]);
    const float sc     = sqrtf(c);
    const float inv_sc = 1.f / sc;
    const float bpos   = softplus_f(pBeta[0]);
    const float bias   = pBias[0];

    const int b = blockIdx.x;
    const int h = b / 80;
    const int t = b % 80;
    int qt, ci;
    if (t < 8)       { qt = t;                ci = 0; }
    else if (t < 24) { qt = 8  + ((t - 8) >> 1);  ci = (t - 8) & 1; }
    else if (t < 48) { qt = 16 + (t - 24) / 3;    ci = (t - 24) % 3; }
    else             { qt = 24 + ((t - 48) >> 2); ci = (t - 48) & 3; }
    const int jt0 = ci * 8;
    const int jt1 = min(jt0 + 8, qt + 1);
    const int q0  = qt << 6;
    const int slot = b;

    const int tid  = threadIdx.x;
    const int lane = tid & 63;
    const int w    = tid >> 6;
    const int wq0  = w * 16;
    const int fr   = lane & 15;
    const int fg   = lane >> 4;

    // stage Q tile (64 rows x 64 k, bf16)
#pragma unroll
    for (int p = 0; p < 2; p++) {
        int idx = tid + p * 256;
        int r = idx >> 3, cb = (idx & 7) * 8;
        *(uint4*)&Qs[r][cb] = *(const uint4*)&Qb[(size_t)(q0 + r) * 1024 + h * 64 + cb];
    }

    float xi[4], dxr[4], mrow[4], lrow[4];
#pragma unroll
    for (int r = 0; r < 4; r++) {
        int row = q0 + wq0 + fg * 4 + r;
        xi[r]   = xns[h * 2048 + row];
        dxr[r]  = xds[h * 2048 + row];
        mrow[r] = -3.0e38f;
        lrow[r] = 0.f;
    }
    f32x4 acc[4] = {};

    for (int jt = jt0; jt < jt1; ++jt) {
        const int k0 = jt << 6;
        __syncthreads();   // prev iter reads done; Qs staged (1st iter)
        // stage K rows + V^T rows (both coalesced 16B)
#pragma unroll
        for (int p = 0; p < 2; p++) {
            int idx = tid + p * 256;
            int r = idx >> 3, cb = (idx & 7) * 8;
            *(uint4*)&Ks[r][cb] = *(const uint4*)&Kb[(size_t)(k0 + r) * 1024 + h * 64 + cb];
            *(uint4*)&Vt[r][cb] = *(const uint4*)&Vtg[(size_t)(h * 64 + r) * 2048 + k0 + cb];
        }
        if (tid < 64)       yl[tid]       = yns[h * 2048 + k0 + tid];
        else if (tid < 128) ydl[tid - 64] = yds[h * 2048 + k0 + tid - 64];
        __syncthreads();

        // ---- S = Q K^T via MFMA ----
        bf16x8 qa0 = *(const bf16x8*)&Qs[wq0 + fr][fg * 8];
        bf16x8 qa1 = *(const bf16x8*)&Qs[wq0 + fr][32 + fg * 8];
        f32x4 sacc[4] = {};
#pragma unroll
        for (int tn = 0; tn < 4; tn++) {
            bf16x8 kb0 = *(const bf16x8*)&Ks[tn * 16 + fr][fg * 8];
            bf16x8 kb1 = *(const bf16x8*)&Ks[tn * 16 + fr][32 + fg * 8];
            sacc[tn] = __builtin_amdgcn_mfma_f32_16x16x32_bf16(qa0, kb0, sacc[tn], 0, 0, 0);
            sacc[tn] = __builtin_amdgcn_mfma_f32_16x16x32_bf16(qa1, kb1, sacc[tn], 0, 0, 0);
        }

        // ---- Poincare score transform ----
        const bool diag = (jt == qt);
        float s[4][4];
#pragma unroll
        for (int tn = 0; tn < 4; tn++) {
            float yj  = yl[tn * 16 + fr];
            float dyj = ydl[tn * 16 + fr];
#pragma unroll
            for (int r = 0; r < 4; r++) {
                float diff = xi[r] - 2.f * sacc[tn][r] + yj;
                float den  = fmaxf(dxr[r] * dyj, EPSF);
                float arg  = 1.f + (2.f * c) * __fdividef(diff, den);
                float z    = fmaxf(arg, 1.f + EPSF);
                float dist = __logf(z + sqrtf(z * z - 1.f)) * inv_sc;
                float sv   = -bpos * dist - bias;
                if (diag && (k0 + tn * 16 + fr > q0 + wq0 + fg * 4 + r)) sv = -3.0e38f;
                s[tn][r] = sv;
            }
        }

        // ---- online softmax per row ----
        float pw[4][4];
#pragma unroll
        for (int r = 0; r < 4; r++) {
            float tm = fmaxf(fmaxf(s[0][r], s[1][r]), fmaxf(s[2][r], s[3][r]));
#pragma unroll
            for (int o = 1; o < 16; o <<= 1) tm = fmaxf(tm, __shfl_xor(tm, o));
            float nm = fmaxf(mrow[r], tm);
            float scalef = __expf(mrow[r] - nm);
            mrow[r] = nm;
            float rs = 0.f;
#pragma unroll
            for (int tn = 0; tn < 4; tn++) {
                float p = (s[tn][r] <= -1.0e38f) ? 0.f : __expf(s[tn][r] - nm);
                pw[tn][r] = p;
                rs += p;
            }
#pragma unroll
            for (int o = 1; o < 16; o <<= 1) rs += __shfl_xor(rs, o);
            lrow[r] = lrow[r] * scalef + rs;
#pragma unroll
            for (int tn = 0; tn < 4; tn++) acc[tn][r] *= scalef;
        }

        // ---- P to wave-private Ps rows (same-wave RAW: no barrier) ----
#pragma unroll
        for (int tn = 0; tn < 4; tn++)
#pragma unroll
            for (int r = 0; r < 4; r++)
                Ps[wq0 + fg * 4 + r][tn * 16 + fr] = f2bf(pw[tn][r]);

        // ---- acc += P V via MFMA ----
        bf16x8 pa0 = *(const bf16x8*)&Ps[wq0 + fr][fg * 8];
        bf16x8 pa1 = *(const bf16x8*)&Ps[wq0 + fr][32 + fg * 8];
#pragma unroll
        for (int tn = 0; tn < 4; tn++) {
            bf16x8 vb0 = *(const bf16x8*)&Vt[tn * 16 + fr][fg * 8];
            bf16x8 vb1 = *(const bf16x8*)&Vt[tn * 16 + fr][32 + fg * 8];
            acc[tn] = __builtin_amdgcn_mfma_f32_16x16x32_bf16(pa0, vb0, acc[tn], 0, 0, 0);
            acc[tn] = __builtin_amdgcn_mfma_f32_16x16x32_bf16(pa1, vb1, acc[tn], 0, 0, 0);
        }
    }

    // ---- write partials (no epilogue here) ----
#pragma unroll
    for (int r = 0; r < 4; r++) {
        int row = wq0 + fg * 4 + r;
        if (fr == 0) {
            ml[(size_t)slot * 128 + row * 2 + 0] = mrow[r];
            ml[(size_t)slot * 128 + row * 2 + 1] = lrow[r];
        }
#pragma unroll
        for (int tn = 0; tn < 4; tn++)
            Og[(size_t)slot * 4096 + row * 64 + tn * 16 + fr] = f2bf(acc[tn][r]);
    }
}

// ---------------- merge partials + exp/log-map epilogue ----------------
// One wave per (h, row). nch = (qt>>3)+1 partials at slot0 = h*80 + prefix(qt).
__global__ __launch_bounds__(256) void k_merge(const unsigned short* __restrict__ Og,
                                               const float* __restrict__ ml,
                                               const float* __restrict__ pLogC,
                                               unsigned short* __restrict__ conc) {
    const float c      = softplus_f(pLogC[0]);
    const float sc     = sqrtf(c);
    const float inv_sc = 1.f / sc;
    int gid  = (blockIdx.x * 256 + threadIdx.x) >> 6;   // 0..32767
    int lane = threadIdx.x & 63;
    int h = gid >> 11, i = gid & 2047;
    int qt = i >> 6, row = i & 63;
    int g = qt >> 3, rr = qt & 7;
    int slot0 = h * 80 + qt + 4 * g * (g - 1) + rr * g;
    int nch = g + 1;

    float M = -3.0e38f;
    for (int k = 0; k < nch; k++)
        M = fmaxf(M, ml[(size_t)(slot0 + k) * 128 + row * 2]);
    float L = 0.f, O = 0.f;
    for (int k = 0; k < nch; k++) {
        float mk = ml[(size_t)(slot0 + k) * 128 + row * 2];
        float lk = ml[(size_t)(slot0 + k) * 128 + row * 2 + 1];
        float e  = __expf(mk - M);
        L += lk * e;
        O += bf2f(Og[(size_t)(slot0 + k) * 4096 + row * 64 + lane]) * e;
    }
    float tv = O / L;
    float n2 = tv * tv;
#pragma unroll
    for (int o = 1; o < 64; o <<= 1) n2 += __shfl_xor(n2, o);
    float nt   = fmaxf(sqrtf(n2), EPSF);
    float f1   = tanhf(sc * nt) / (sc * nt);
    float ny   = fmaxf(f1 * sqrtf(n2), EPSF);
    float ncl  = fminf(ny, inv_sc - EPSF);
    float coef = atanhf(sc * ncl) / (sc * ny);
    conc[(size_t)i * 1024 + h * 64 + lane] = f2bf(coef * f1 * tv);
}

// ---------------- launch ----------------
// ws layout (39.1 MB peak, within empirically-proven 41 MB):
//   0-4:   xb (x bf16)        -> reused as Vtg after V GEMM
//   4-6:   wqb | 6-8: wkb | 8-10: wvb | 10-12: wob
//   12-16: Qtb | 16-20: Ktb | 20-24: Vb | 24-28: concb
//   28-28.5: xns/yns/xds/yds
//   28.5-38.5: Og (bf16 partials, 1280 slots x 64 x 64 = 10 MiB)
//   38.5-39.125: ml (fp32, 1280 x 64 x 2)
extern "C" void kernel_launch(void* const* d_in, const int* in_sizes, int n_in,
                              void* d_out, int out_size, void* d_ws, size_t ws_size,
                              hipStream_t stream) {
    const float* x     = (const float*)d_in[0];
    const float* Wq    = (const float*)d_in[1];
    const float* Wk    = (const float*)d_in[2];
    const float* Wv    = (const float*)d_in[3];
    const float* Wo    = (const float*)d_in[4];
    const float* pLogC = (const float*)d_in[5];
    const float* pBeta = (const float*)d_in[6];
    const float* pBias = (const float*)d_in[7];
    float* out = (float*)d_out;

    char* w = (char*)d_ws;
    unsigned short* xb    = (unsigned short*)(w);
    unsigned short* Vtg   = (unsigned short*)(w);               // reuse xb after GEMMs
    unsigned short* wqb   = (unsigned short*)(w + (4u  << 20));
    unsigned short* wkb   = (unsigned short*)(w + (6u  << 20));
    unsigned short* wvb   = (unsigned short*)(w + (8u  << 20));
    unsigned short* wob   = (unsigned short*)(w + (10u << 20));
    unsigned short* Qtb   = (unsigned short*)(w + (12u << 20));
    unsigned short* Ktb   = (unsigned short*)(w + (16u << 20));
    unsigned short* Vb    = (unsigned short*)(w + (20u << 20));
    unsigned short* concb = (unsigned short*)(w + (24u << 20));
    float*          xns   = (float*)(w + (28u << 20));
    float*          yns   = (float*)(w + (28u << 20) + (1u << 17));
    float*          xds   = (float*)(w + (28u << 20) + (2u << 17));
    float*          yds   = (float*)(w + (28u << 20) + (3u << 17));
    unsigned short* Og    = (unsigned short*)(w + (28u << 20) + (1u << 19));
    float*          ml    = (float*)(w + (38u << 20) + (1u << 19));

    k_f2b<<<2048, 256, 0, stream>>>(x, xb, 2048 * 1024);
    k_f2bw<<<2048, 256, 0, stream>>>(Wq, Wk, Wv, Wo, wqb, wkb, wvb, wob);

    k_gemm_mfma<1><<<256, 256, 0, stream>>>(xb, wqb, Qtb, 2048, 1024, 1024);
    k_gemm_mfma<1><<<256, 256, 0, stream>>>(xb, wkb, Ktb, 2048, 1024, 1024);
    k_gemm_mfma<1><<<256, 256, 0, stream>>>(xb, wvb, Vb,  2048, 1024, 1024);

    k_vt<<<512, 256, 0, stream>>>(Vb, Vtg);          // xb dead from here

    k_expmap_b<<<8192, 256, 0, stream>>>(Qtb, xns, xds, pLogC);
    k_expmap_b<<<8192, 256, 0, stream>>>(Ktb, yns, yds, pLogC);

    k_attn_part<<<1280, 256, 0, stream>>>(Qtb, Ktb, Vtg, xns, xds, yns, yds,
                                          pLogC, pBeta, pBias, Og, ml);

    k_merge<<<8192, 256, 0, stream>>>(Og, ml, pLogC, concb);

    k_gemm_mfma<0><<<256, 256, 0, stream>>>(concb, wob, out, 2048, 1024, 1024);
}